// Round 1
// baseline (6440.643 us; speedup 1.0000x reference)
//
#include <hip/hip_runtime.h>
#include <hip/hip_bf16.h>
#include <cstddef>

#define BB   4096
#define TT   64
#define OBSN 16
#define NST  8
#define LAT  32
#define HID  64
#define NK   8
#define BLK  128

__device__ __forceinline__ float fast_tanh(float x) {
    // tanh(x) = 1 - 2/(exp(2x)+1); exact at +/-inf, branchless
    float e = __expf(2.0f * x);
    return 1.0f - 2.0f / (e + 1.0f);
}

__global__ __launch_bounds__(BLK) void node_fused(
    const float* __restrict__ tg, const float* __restrict__ xg,
    const float* __restrict__ zg,
    const float* __restrict__ eW1, const float* __restrict__ eb1,
    const float* __restrict__ eW2, const float* __restrict__ eb2,
    const float* __restrict__ eW3, const float* __restrict__ eb3,
    const float* __restrict__ oW1, const float* __restrict__ ob1,
    const float* __restrict__ oW2, const float* __restrict__ ob2,
    const float* __restrict__ oW3, const float* __restrict__ ob3,
    const float* __restrict__ dW, const float* __restrict__ db,
    float* __restrict__ outg)
{
    // Column-private LDS scratch: [row][tid] so lanes are consecutive dwords
    // (2-way bank aliasing = free). Enables runtime-indexed activation reads
    // without spilling register arrays to scratch.
    __shared__ float zbuf[LAT][BLK];
    __shared__ float hbuf[HID][BLK];

    const int c = threadIdx.x;
    const int k = blockIdx.x / (BB / BLK);
    const int b = (blockIdx.x % (BB / BLK)) * BLK + c;

    const float* W1 = oW1 + k * (LAT * HID);
    const float* B1 = ob1 + k * HID;
    const float* W2 = oW2 + k * (HID * HID);
    const float* B2 = ob2 + k * HID;
    const float* W3 = oW3 + k * (HID * LAT);
    const float* B3 = ob3 + k * LAT;

    // ---------------- encoder: concat(x[b,0,:], z[b,:]) -> 64 -> 64 -> 32 ----
    {
        const float* xr = xg + (size_t)b * (TT * OBSN);
        #pragma unroll
        for (int o = 0; o < OBSN; ++o) hbuf[o][c] = xr[o];
        const float* zr = zg + (size_t)b * NST;
        #pragma unroll
        for (int s = 0; s < NST; ++s) hbuf[OBSN + s][c] = zr[s];
    }

    float acc[HID];
    #pragma unroll
    for (int j = 0; j < HID; ++j) acc[j] = eb1[j];
    #pragma unroll 4
    for (int i = 0; i < OBSN + NST; ++i) {
        float v = hbuf[i][c];
        const float* wr = eW1 + i * HID;
        #pragma unroll
        for (int j = 0; j < HID; ++j) acc[j] = fmaf(v, wr[j], acc[j]);
    }
    #pragma unroll
    for (int j = 0; j < HID; ++j) hbuf[j][c] = fast_tanh(acc[j]);

    #pragma unroll
    for (int j = 0; j < HID; ++j) acc[j] = eb2[j];
    #pragma unroll 4
    for (int i = 0; i < HID; ++i) {
        float v = hbuf[i][c];
        const float* wr = eW2 + i * HID;
        #pragma unroll
        for (int j = 0; j < HID; ++j) acc[j] = fmaf(v, wr[j], acc[j]);
    }
    #pragma unroll
    for (int j = 0; j < HID; ++j) hbuf[j][c] = fast_tanh(acc[j]);

    float zc[LAT];
    #pragma unroll
    for (int l = 0; l < LAT; ++l) zc[l] = eb3[l];
    #pragma unroll 4
    for (int i = 0; i < HID; ++i) {
        float v = hbuf[i][c];
        const float* wr = eW3 + i * LAT;
        #pragma unroll
        for (int l = 0; l < LAT; ++l) zc[l] = fmaf(v, wr[l], zc[l]);
    }
    #pragma unroll
    for (int l = 0; l < LAT; ++l) zbuf[l][c] = zc[l];

    float* outb = outg + (size_t)(k * BB + b) * (TT * OBSN);

    // ---------------- decode t = 0 ----------------
    {
        float oa[OBSN];
        #pragma unroll
        for (int o = 0; o < OBSN; ++o) oa[o] = db[o];
        #pragma unroll 4
        for (int l = 0; l < LAT; ++l) {
            float v = zbuf[l][c];
            const float* wr = dW + l * OBSN;
            #pragma unroll
            for (int o = 0; o < OBSN; ++o) oa[o] = fmaf(v, wr[o], oa[o]);
        }
        float4* dst = (float4*)outb;
        dst[0] = make_float4(oa[0],  oa[1],  oa[2],  oa[3]);
        dst[1] = make_float4(oa[4],  oa[5],  oa[6],  oa[7]);
        dst[2] = make_float4(oa[8],  oa[9],  oa[10], oa[11]);
        dst[3] = make_float4(oa[12], oa[13], oa[14], oa[15]);
    }

    // ---------------- RK4 time loop ----------------
    float tprev = tg[0];
    for (int step = 1; step < TT; ++step) {
        const float tcur = tg[step];
        const float h = tcur - tprev;
        tprev = tcur;

        float zn[LAT];
        #pragma unroll
        for (int l = 0; l < LAT; ++l) zn[l] = zc[l];

        // invariant: zbuf holds the f-input for the current stage
        #pragma unroll 1
        for (int stage = 0; stage < 4; ++stage) {
            // ---- f(zbuf) : 32 -> 64 tanh -> 64 tanh -> 32 ----
            float a[HID];
            #pragma unroll
            for (int j = 0; j < HID; ++j) a[j] = B1[j];
            #pragma unroll 4
            for (int i = 0; i < LAT; ++i) {
                float v = zbuf[i][c];
                const float* wr = W1 + i * HID;
                #pragma unroll
                for (int j = 0; j < HID; ++j) a[j] = fmaf(v, wr[j], a[j]);
            }
            #pragma unroll
            for (int j = 0; j < HID; ++j) hbuf[j][c] = fast_tanh(a[j]);

            #pragma unroll
            for (int j = 0; j < HID; ++j) a[j] = B2[j];
            #pragma unroll 4
            for (int i = 0; i < HID; ++i) {
                float v = hbuf[i][c];
                const float* wr = W2 + i * HID;
                #pragma unroll
                for (int j = 0; j < HID; ++j) a[j] = fmaf(v, wr[j], a[j]);
            }
            #pragma unroll
            for (int j = 0; j < HID; ++j) hbuf[j][c] = fast_tanh(a[j]);

            float fo[LAT];
            #pragma unroll
            for (int l = 0; l < LAT; ++l) fo[l] = B3[l];
            #pragma unroll 4
            for (int i = 0; i < HID; ++i) {
                float v = hbuf[i][c];
                const float* wr = W3 + i * LAT;
                #pragma unroll
                for (int l = 0; l < LAT; ++l) fo[l] = fmaf(v, wr[l], fo[l]);
            }

            // ---- RK4 combine ----
            const float czn = (stage == 0 || stage == 3) ? h * (1.0f / 6.0f)
                                                         : h * (1.0f / 3.0f);
            #pragma unroll
            for (int l = 0; l < LAT; ++l) zn[l] += czn * fo[l];

            if (stage < 3) {
                const float czt = (stage == 2) ? h : 0.5f * h;
                #pragma unroll
                for (int l = 0; l < LAT; ++l) zbuf[l][c] = zc[l] + czt * fo[l];
            } else {
                #pragma unroll
                for (int l = 0; l < LAT; ++l) { zc[l] = zn[l]; zbuf[l][c] = zn[l]; }
            }
        }

        // ---- decode + store this step ----
        {
            float oa[OBSN];
            #pragma unroll
            for (int o = 0; o < OBSN; ++o) oa[o] = db[o];
            #pragma unroll 4
            for (int l = 0; l < LAT; ++l) {
                float v = zbuf[l][c];
                const float* wr = dW + l * OBSN;
                #pragma unroll
                for (int o = 0; o < OBSN; ++o) oa[o] = fmaf(v, wr[o], oa[o]);
            }
            float4* dst = (float4*)(outb + (size_t)step * OBSN);
            dst[0] = make_float4(oa[0],  oa[1],  oa[2],  oa[3]);
            dst[1] = make_float4(oa[4],  oa[5],  oa[6],  oa[7]);
            dst[2] = make_float4(oa[8],  oa[9],  oa[10], oa[11]);
            dst[3] = make_float4(oa[12], oa[13], oa[14], oa[15]);
        }
    }
}

extern "C" void kernel_launch(void* const* d_in, const int* in_sizes, int n_in,
                              void* d_out, int out_size, void* d_ws, size_t ws_size,
                              hipStream_t stream) {
    const float* tg  = (const float*)d_in[0];
    const float* xg  = (const float*)d_in[1];
    const float* zg  = (const float*)d_in[2];
    const float* eW1 = (const float*)d_in[3];
    const float* eb1 = (const float*)d_in[4];
    const float* eW2 = (const float*)d_in[5];
    const float* eb2 = (const float*)d_in[6];
    const float* eW3 = (const float*)d_in[7];
    const float* eb3 = (const float*)d_in[8];
    const float* oW1 = (const float*)d_in[9];
    const float* ob1 = (const float*)d_in[10];
    const float* oW2 = (const float*)d_in[11];
    const float* ob2 = (const float*)d_in[12];
    const float* oW3 = (const float*)d_in[13];
    const float* ob3 = (const float*)d_in[14];
    const float* dW  = (const float*)d_in[15];
    const float* db  = (const float*)d_in[16];
    float* outg = (float*)d_out;

    dim3 grid(NK * (BB / BLK));  // 8 * 32 = 256 blocks, one per CU
    node_fused<<<grid, BLK, 0, stream>>>(
        tg, xg, zg, eW1, eb1, eW2, eb2, eW3, eb3,
        oW1, ob1, oW2, ob2, oW3, ob3, dW, db, outg);
}

// Round 2
// 6370.613 us; speedup vs baseline: 1.0110x; 1.0110x over previous
//
#include <hip/hip_runtime.h>
#include <cstddef>

#define BB    4096
#define TT    64
#define OBSN  16
#define NSTAT 8
#define LAT   32
#define HID   64
#define NK    8
#define M     8          // samples per wave
#define NW    4          // waves per block
#define BLK   (NW * 64)
#define ZS    36         // z-buffer stride (floats), 144B (16B aligned, banks spread)
#define HS    68         // h-buffer stride (floats), 272B

__device__ __forceinline__ float fast_tanh(float x) {
    // tanh(x) = 1 - 2/(exp(2x)+1); branchless, exact at +/-inf
    float e = __expf(2.0f * x);
    return 1.0f - 2.0f / (e + 1.0f);
}

// One output neuron (this lane's j) of a dense layer for one sample.
// act: LDS pointer (uniform or per-lane-half address) -> broadcast ds_read_b128.
// w:   per-lane weight column held in VGPRs (indices all compile-time).
template<int NIN>
__device__ __forceinline__ float layer_acc(const float* act, const float* w, float bias) {
    float a0 = bias, a1 = 0.0f;
    #pragma unroll
    for (int iq = 0; iq < NIN / 4; ++iq) {
        float4 v = *(const float4*)(act + iq * 4);
        a0 = fmaf(v.x, w[iq * 4 + 0], a0);
        a1 = fmaf(v.y, w[iq * 4 + 1], a1);
        a0 = fmaf(v.z, w[iq * 4 + 2], a0);
        a1 = fmaf(v.w, w[iq * 4 + 3], a1);
    }
    return a0 + a1;
}

// Decode all M samples at step t from zb (lane = (sample-quad, o)).
__device__ __forceinline__ void decode_store(const float* zb, const float* dw, float dbr,
                                             float* outp, int t, int lane) {
    const int o = lane & 15;
    const int q = lane >> 4;  // 4 samples per wave-instruction
    #pragma unroll
    for (int r = 0; r < 2; ++r) {
        const int sm = r * 4 + q;
        float a0 = dbr, a1 = 0.0f;
        #pragma unroll
        for (int lq = 0; lq < LAT / 4; ++lq) {
            float4 v = *(const float4*)(zb + sm * ZS + lq * 4);
            a0 = fmaf(v.x, dw[lq * 4 + 0], a0);
            a1 = fmaf(v.y, dw[lq * 4 + 1], a1);
            a0 = fmaf(v.z, dw[lq * 4 + 2], a0);
            a1 = fmaf(v.w, dw[lq * 4 + 3], a1);
        }
        outp[((size_t)sm * TT + t) * OBSN + o] = a0 + a1;
    }
}

__global__ __launch_bounds__(BLK, 2) void node_lanej(
    const float* __restrict__ tg, const float* __restrict__ xg,
    const float* __restrict__ zg,
    const float* __restrict__ eW1, const float* __restrict__ eb1,
    const float* __restrict__ eW2, const float* __restrict__ eb2,
    const float* __restrict__ eW3, const float* __restrict__ eb3,
    const float* __restrict__ oW1, const float* __restrict__ ob1,
    const float* __restrict__ oW2, const float* __restrict__ ob2,
    const float* __restrict__ oW3, const float* __restrict__ ob3,
    const float* __restrict__ dWg, const float* __restrict__ dbg,
    float* __restrict__ outg)
{
    // Per-wave private LDS (no cross-wave sharing -> no __syncthreads anywhere).
    __shared__ __align__(16) float zb_all[NW][M * ZS];
    __shared__ __align__(16) float hb_all[NW][M * HS];

    const int lane = threadIdx.x & 63;
    const int wid  = threadIdx.x >> 6;
    float* zb = zb_all[wid];
    float* hb = hb_all[wid];

    const int k     = blockIdx.x >> 7;                       // 128 blocks per k
    const int bbase = (blockIdx.x & 127) * (M * NW) + wid * M;
    const int half  = lane >> 5;                             // sample parity for pair ops
    const int l31   = lane & 31;

    float* outp = outg + (size_t)(k * BB + bbase) * (TT * OBSN);

    // Decoder weights (used every step) — lane&15 column.
    float dw[LAT];
    #pragma unroll
    for (int l = 0; l < LAT; ++l) dw[l] = dWg[l * OBSN + (lane & 15)];
    const float dbr = dbg[lane & 15];

    // RK4 state, pair-packed: zc[p] = z[2p + half][l31]
    float zc[M / 2];

    // ---------------- encoder (run once; k-redundant but 1/250 of the work) ---
    {
        // stage inputs: concat(x[b,0,:], z[b,:]) -> 24 values per sample
        #pragma unroll
        for (int m = 0; m < M; ++m) {
            const int b = bbase + m;
            float v = 0.0f;
            if (lane < OBSN)                 v = xg[(size_t)b * (TT * OBSN) + lane];
            else if (lane < OBSN + NSTAT)    v = zg[(size_t)b * NSTAT + (lane - OBSN)];
            if (lane < OBSN + NSTAT)         hb[m * HS + lane] = v;
        }

        float ew1[OBSN + NSTAT];
        #pragma unroll
        for (int i = 0; i < OBSN + NSTAT; ++i) ew1[i] = eW1[i * HID + lane];
        const float e1b = eb1[lane];

        float t1[M];
        #pragma unroll
        for (int m = 0; m < M; ++m) t1[m] = layer_acc<OBSN + NSTAT>(hb + m * HS, ew1, e1b);

        float ew2[HID];
        #pragma unroll
        for (int i = 0; i < HID; ++i) ew2[i] = eW2[i * HID + lane];
        const float e2b = eb2[lane];

        #pragma unroll
        for (int m = 0; m < M; ++m) hb[m * HS + lane] = fast_tanh(t1[m]);
        float t2[M];
        #pragma unroll
        for (int m = 0; m < M; ++m) t2[m] = layer_acc<HID>(hb + m * HS, ew2, e2b);
        #pragma unroll
        for (int m = 0; m < M; ++m) hb[m * HS + lane] = fast_tanh(t2[m]);

        float ew3[HID];
        #pragma unroll
        for (int i = 0; i < HID; ++i) ew3[i] = eW3[i * LAT + l31];
        const float e3b = eb3[l31];

        #pragma unroll
        for (int p = 0; p < M / 2; ++p) {
            zc[p] = layer_acc<HID>(hb + (2 * p + half) * HS, ew3, e3b);
            zb[(2 * p + half) * ZS + l31] = zc[p];
        }
    }

    // ---------------- ODE weights resident in VGPRs --------------------------
    float w1[LAT];
    #pragma unroll
    for (int i = 0; i < LAT; ++i) w1[i] = oW1[k * (LAT * HID) + i * HID + lane];
    float w2[HID];
    #pragma unroll
    for (int i = 0; i < HID; ++i) w2[i] = oW2[k * (HID * HID) + i * HID + lane];
    float w3[HID];
    #pragma unroll
    for (int i = 0; i < HID; ++i) w3[i] = oW3[k * (HID * LAT) + i * LAT + l31];
    const float b1r = ob1[k * HID + lane];
    const float b2r = ob2[k * HID + lane];
    const float b3r = ob3[k * LAT + l31];

    // ---------------- decode t = 0 --------------------------------------------
    decode_store(zb, dw, dbr, outp, 0, lane);

    // ---------------- RK4 time loop -------------------------------------------
    float tprev = tg[0];
    for (int step = 1; step < TT; ++step) {
        const float tcur = tg[step];
        const float h = tcur - tprev;
        tprev = tcur;

        float zn[M / 2];
        #pragma unroll
        for (int p = 0; p < M / 2; ++p) zn[p] = zc[p];

        #pragma unroll 1
        for (int stage = 0; stage < 4; ++stage) {
            // ---- f(zb) : 32 -> 64 tanh -> 64 tanh -> 32 ----
            float t1[M];
            #pragma unroll
            for (int m = 0; m < M; ++m) t1[m] = layer_acc<LAT>(zb + m * ZS, w1, b1r);
            #pragma unroll
            for (int m = 0; m < M; ++m) hb[m * HS + lane] = fast_tanh(t1[m]);

            float t2[M];
            #pragma unroll
            for (int m = 0; m < M; ++m) t2[m] = layer_acc<HID>(hb + m * HS, w2, b2r);
            #pragma unroll
            for (int m = 0; m < M; ++m) hb[m * HS + lane] = fast_tanh(t2[m]);

            // layer 3: pair-packed (2 samples across lane halves)
            float fo[M / 2];
            #pragma unroll
            for (int p = 0; p < M / 2; ++p)
                fo[p] = layer_acc<HID>(hb + (2 * p + half) * HS, w3, b3r);

            // ---- RK4 combine ----
            const float czn = (stage == 0 || stage == 3) ? h * (1.0f / 6.0f)
                                                         : h * (1.0f / 3.0f);
            #pragma unroll
            for (int p = 0; p < M / 2; ++p) zn[p] = fmaf(czn, fo[p], zn[p]);

            if (stage < 3) {
                const float czt = (stage == 2) ? h : 0.5f * h;
                #pragma unroll
                for (int p = 0; p < M / 2; ++p)
                    zb[(2 * p + half) * ZS + l31] = fmaf(czt, fo[p], zc[p]);
            } else {
                #pragma unroll
                for (int p = 0; p < M / 2; ++p) {
                    zc[p] = zn[p];
                    zb[(2 * p + half) * ZS + l31] = zn[p];
                }
            }
        }

        decode_store(zb, dw, dbr, outp, step, lane);
    }
}

extern "C" void kernel_launch(void* const* d_in, const int* in_sizes, int n_in,
                              void* d_out, int out_size, void* d_ws, size_t ws_size,
                              hipStream_t stream) {
    const float* tg  = (const float*)d_in[0];
    const float* xg  = (const float*)d_in[1];
    const float* zg  = (const float*)d_in[2];
    const float* eW1 = (const float*)d_in[3];
    const float* eb1 = (const float*)d_in[4];
    const float* eW2 = (const float*)d_in[5];
    const float* eb2 = (const float*)d_in[6];
    const float* eW3 = (const float*)d_in[7];
    const float* eb3 = (const float*)d_in[8];
    const float* oW1 = (const float*)d_in[9];
    const float* ob1 = (const float*)d_in[10];
    const float* oW2 = (const float*)d_in[11];
    const float* ob2 = (const float*)d_in[12];
    const float* oW3 = (const float*)d_in[13];
    const float* ob3 = (const float*)d_in[14];
    const float* dW  = (const float*)d_in[15];
    const float* db  = (const float*)d_in[16];
    float* outg = (float*)d_out;

    dim3 grid(NK * (BB / (M * NW)));  // 8 * 128 = 1024 blocks, 4096 waves
    node_lanej<<<grid, BLK, 0, stream>>>(
        tg, xg, zg, eW1, eb1, eW2, eb2, eW3, eb3,
        oW1, ob1, oW2, ob2, oW3, ob3, dW, db, outg);
}

// Round 4
// 4387.774 us; speedup vs baseline: 1.4679x; 1.4519x over previous
//
#include <hip/hip_runtime.h>
#include <cstddef>

#define BB    4096
#define TT    64
#define OBSN  16
#define NSTAT 8
#define LAT   32
#define HID   64
#define NK    8
#define SMP   64      // samples per block (= lanes per wave)
#define NWV   8       // waves per block
#define BLK   (NWV * 64)
#define HS    68      // hidden-activation row stride (dwords); 68/4=17 odd -> conflict-free b128
#define ZSS   36      // z row stride (dwords); 36/4=9 odd -> conflict-free b128

__device__ __forceinline__ float fast_tanh(float x) {
    // tanh(x) = 1 - 2/(exp(2x)+1); branchless, exact at +/-inf
    float e = __expf(2.0f * x);
    return 1.0f - 2.0f / (e + 1.0f);
}

// Dense layer, j-chunk per wave. lane = sample. in_row: this lane's LDS row
// (vector ds_read_b128). W/Bv: global row-major [NIN][NOUT], indices wave-uniform
// (j0 derives from readfirstlane'd wid) -> scalar loads feeding v_fma's SGPR slot.
template<int NIN, int NOUT, int JCN>
__device__ __forceinline__ void dense_jc(const float* __restrict__ in_row,
                                         const float* __restrict__ W,
                                         const float* __restrict__ Bv,
                                         int j0, float* acc) {
    #pragma unroll
    for (int j = 0; j < JCN; ++j) acc[j] = Bv[j0 + j];
    #pragma unroll
    for (int iq = 0; iq < NIN / 4; ++iq) {
        float4 v = *(const float4*)(in_row + iq * 4);
        const float* Wr = W + (iq * 4) * NOUT + j0;
        #pragma unroll
        for (int j = 0; j < JCN; ++j) acc[j] = fmaf(v.x, Wr[j], acc[j]);
        #pragma unroll
        for (int j = 0; j < JCN; ++j) acc[j] = fmaf(v.y, Wr[NOUT + j], acc[j]);
        #pragma unroll
        for (int j = 0; j < JCN; ++j) acc[j] = fmaf(v.z, Wr[2 * NOUT + j], acc[j]);
        #pragma unroll
        for (int j = 0; j < JCN; ++j) acc[j] = fmaf(v.w, Wr[3 * NOUT + j], acc[j]);
    }
}

__global__ __launch_bounds__(BLK, 4) void node_jsplit(
    const float* __restrict__ tg, const float* __restrict__ xg,
    const float* __restrict__ zg,
    const float* __restrict__ eW1, const float* __restrict__ eb1,
    const float* __restrict__ eW2, const float* __restrict__ eb2,
    const float* __restrict__ eW3, const float* __restrict__ eb3,
    const float* __restrict__ oW1, const float* __restrict__ ob1,
    const float* __restrict__ oW2, const float* __restrict__ ob2,
    const float* __restrict__ oW3, const float* __restrict__ ob3,
    const float* __restrict__ dWg, const float* __restrict__ dbg,
    float* __restrict__ outg)
{
    __shared__ __align__(16) float hb0[SMP][HS];
    __shared__ __align__(16) float hb1[SMP][HS];
    __shared__ __align__(16) float zbuf[SMP][ZSS];

    const int lane = threadIdx.x & 63;                                   // sample
    const int wid  = __builtin_amdgcn_readfirstlane((int)(threadIdx.x >> 6));
    const int k     = blockIdx.x >> 6;                                   // 64 blocks / k
    const int sbase = (blockIdx.x & 63) * SMP;
    const int b     = sbase + lane;
    const int j0 = wid * 8;   // layer1/2 output chunk
    const int j3 = wid * 4;   // layer3 (32-wide) output chunk
    const int od = wid * 2;   // decode (16-wide) output chunk

    const float* W1 = oW1 + k * (LAT * HID);
    const float* B1 = ob1 + k * HID;
    const float* W2 = oW2 + k * (HID * HID);
    const float* B2 = ob2 + k * HID;
    const float* W3 = oW3 + k * (HID * LAT);
    const float* B3 = ob3 + k * LAT;

    // ---- stage encoder input: concat(x[b,0,:16], z[b,:8]) -> hb0[s][0..23] ----
    if (wid == 0) {
        const float4* xr = (const float4*)(xg + (size_t)b * (TT * OBSN));
        float4* dst = (float4*)&hb0[lane][0];
        dst[0] = xr[0]; dst[1] = xr[1]; dst[2] = xr[2]; dst[3] = xr[3];
        const float4* zr = (const float4*)(zg + (size_t)b * NSTAT);
        dst[4] = zr[0]; dst[5] = zr[1];
    }
    __syncthreads();

    float acc[8];
    // ---- encoder L1: 24 -> 64, tanh -> hb1 ----
    dense_jc<OBSN + NSTAT, HID, 8>(&hb0[lane][0], eW1, eb1, j0, acc);
    {
        float4* o = (float4*)&hb1[lane][j0];
        o[0] = make_float4(fast_tanh(acc[0]), fast_tanh(acc[1]), fast_tanh(acc[2]), fast_tanh(acc[3]));
        o[1] = make_float4(fast_tanh(acc[4]), fast_tanh(acc[5]), fast_tanh(acc[6]), fast_tanh(acc[7]));
    }
    __syncthreads();
    // ---- encoder L2: 64 -> 64, tanh -> hb0 ----
    dense_jc<HID, HID, 8>(&hb1[lane][0], eW2, eb2, j0, acc);
    {
        float4* o = (float4*)&hb0[lane][j0];
        o[0] = make_float4(fast_tanh(acc[0]), fast_tanh(acc[1]), fast_tanh(acc[2]), fast_tanh(acc[3]));
        o[1] = make_float4(fast_tanh(acc[4]), fast_tanh(acc[5]), fast_tanh(acc[6]), fast_tanh(acc[7]));
    }
    __syncthreads();
    // ---- encoder L3: 64 -> 32 (linear) -> z0 chunk ----
    float zc[4];
    dense_jc<HID, LAT, 4>(&hb0[lane][0], eW3, eb3, j3, zc);
    *(float4*)&zbuf[lane][j3] = make_float4(zc[0], zc[1], zc[2], zc[3]);
    __syncthreads();

    float* outp = outg + ((size_t)(k * BB + b)) * (TT * OBSN) + od;

    // ---- decode t = 0 ----
    {
        float oa[2];
        dense_jc<LAT, OBSN, 2>(&zbuf[lane][0], dWg, dbg, od, oa);
        *(float2*)outp = make_float2(oa[0], oa[1]);
    }

    // ---- RK4 time loop ----
    float tprev = tg[0];
    #pragma unroll 1
    for (int step = 1; step < TT; ++step) {
        const float tcur = tg[step];
        const float h = tcur - tprev;
        tprev = tcur;

        float zn[4];
        #pragma unroll
        for (int p = 0; p < 4; ++p) zn[p] = zc[p];

        #pragma unroll 1
        for (int stage = 0; stage < 4; ++stage) {
            // L1: zbuf(32) -> hb0(64) tanh
            dense_jc<LAT, HID, 8>(&zbuf[lane][0], W1, B1, j0, acc);
            {
                float4* o = (float4*)&hb0[lane][j0];
                o[0] = make_float4(fast_tanh(acc[0]), fast_tanh(acc[1]), fast_tanh(acc[2]), fast_tanh(acc[3]));
                o[1] = make_float4(fast_tanh(acc[4]), fast_tanh(acc[5]), fast_tanh(acc[6]), fast_tanh(acc[7]));
            }
            __syncthreads();
            // L2: hb0(64) -> hb1(64) tanh
            dense_jc<HID, HID, 8>(&hb0[lane][0], W2, B2, j0, acc);
            {
                float4* o = (float4*)&hb1[lane][j0];
                o[0] = make_float4(fast_tanh(acc[0]), fast_tanh(acc[1]), fast_tanh(acc[2]), fast_tanh(acc[3]));
                o[1] = make_float4(fast_tanh(acc[4]), fast_tanh(acc[5]), fast_tanh(acc[6]), fast_tanh(acc[7]));
            }
            __syncthreads();
            // L3: hb1(64) -> f(32) chunk, + RK4 combine
            float fo[4];
            dense_jc<HID, LAT, 4>(&hb1[lane][0], W3, B3, j3, fo);

            const float czn = (stage == 0 || stage == 3) ? h * (1.0f / 6.0f)
                                                         : h * (1.0f / 3.0f);
            #pragma unroll
            for (int p = 0; p < 4; ++p) zn[p] = fmaf(czn, fo[p], zn[p]);

            if (stage < 3) {
                const float czt = (stage == 2) ? h : 0.5f * h;
                float4 zt;
                zt.x = fmaf(czt, fo[0], zc[0]);
                zt.y = fmaf(czt, fo[1], zc[1]);
                zt.z = fmaf(czt, fo[2], zc[2]);
                zt.w = fmaf(czt, fo[3], zc[3]);
                *(float4*)&zbuf[lane][j3] = zt;
            } else {
                #pragma unroll
                for (int p = 0; p < 4; ++p) zc[p] = zn[p];
                *(float4*)&zbuf[lane][j3] = make_float4(zn[0], zn[1], zn[2], zn[3]);
            }
            __syncthreads();
        }

        // decode this step (reads zbuf after the stage-3 barrier)
        {
            float oa[2];
            dense_jc<LAT, OBSN, 2>(&zbuf[lane][0], dWg, dbg, od, oa);
            *(float2*)(outp + (size_t)step * OBSN) = make_float2(oa[0], oa[1]);
        }
    }
}

extern "C" void kernel_launch(void* const* d_in, const int* in_sizes, int n_in,
                              void* d_out, int out_size, void* d_ws, size_t ws_size,
                              hipStream_t stream) {
    const float* tg  = (const float*)d_in[0];
    const float* xg  = (const float*)d_in[1];
    const float* zg  = (const float*)d_in[2];
    const float* eW1 = (const float*)d_in[3];
    const float* eb1 = (const float*)d_in[4];
    const float* eW2 = (const float*)d_in[5];
    const float* eb2 = (const float*)d_in[6];
    const float* eW3 = (const float*)d_in[7];
    const float* eb3 = (const float*)d_in[8];
    const float* oW1 = (const float*)d_in[9];
    const float* ob1 = (const float*)d_in[10];
    const float* oW2 = (const float*)d_in[11];
    const float* ob2 = (const float*)d_in[12];
    const float* oW3 = (const float*)d_in[13];
    const float* ob3 = (const float*)d_in[14];
    const float* dW  = (const float*)d_in[15];
    const float* db  = (const float*)d_in[16];
    float* outg = (float*)d_out;

    dim3 grid(NK * (BB / SMP));  // 8 * 64 = 512 blocks, 4096 waves
    node_jsplit<<<grid, BLK, 0, stream>>>(
        tg, xg, zg, eW1, eb1, eW2, eb2, eW3, eb3,
        oW1, ob1, oW2, ob2, oW3, ob3, dW, db, outg);
}

// Round 5
// 3287.813 us; speedup vs baseline: 1.9589x; 1.3346x over previous
//
#include <hip/hip_runtime.h>
#include <cstddef>

#define BB    4096
#define TT    64
#define OBSN  16
#define NSTAT 8
#define LAT   32
#define HID   64
#define NK    8
#define SMP   64      // samples per block (= lanes per wave)
#define NWV   8       // waves per block
#define BLK   (NWV * 64)
#define HSTR  68      // H row stride (dwords); 68 % 32 == 4 -> 8-lane groups tile all banks (b128 conflict-free)
#define ZSTR  36      // ZB row stride (dwords); 36 % 32 == 4 -> same property

// LDS weight arena layout (float offsets)
#define WO_W1  0       // [32][64]  = 2048
#define WO_W2  2048    // [64][64]  = 4096
#define WO_W3  6144    // [64][32]  = 2048
#define WO_B1  8192    // 64
#define WO_B2  8256    // 64
#define WO_B3  8320    // 32
#define WO_DW  8352    // [32][16]  = 512
#define WO_DB  8864    // 16
#define WTOT   8880

__device__ __forceinline__ float fast_tanh(float x) {
    // tanh(x) = 1 - 2/(exp(2x)+1); branchless, exact at +/-inf
    float e = __expf(2.0f * x);
    return 1.0f - 2.0f / (e + 1.0f);
}

// Dense layer j-chunk. act: this lane's LDS activation row (per-lane b128 reads,
// conflict-free strides). Wj/Bj: pre-offset (by j-chunk) weight/bias pointers —
// LDS uniform addresses -> broadcast ds_read_b128 with immediate offsets, zero
// per-load VALU. (Encoder passes global pointers; runs once, cost negligible.)
template<int NIN, int NOUT, int JCN>
__device__ __forceinline__ void dense_any(const float* __restrict__ act,
                                          const float* __restrict__ Wj,
                                          const float* __restrict__ Bj,
                                          float* acc) {
    if constexpr (JCN >= 4) {
        #pragma unroll
        for (int j = 0; j < JCN; j += 4) {
            float4 b4 = *(const float4*)(Bj + j);
            acc[j] = b4.x; acc[j + 1] = b4.y; acc[j + 2] = b4.z; acc[j + 3] = b4.w;
        }
    } else {
        float2 b2 = *(const float2*)Bj;
        acc[0] = b2.x; acc[1] = b2.y;
    }
    #pragma unroll
    for (int iq = 0; iq < NIN / 4; ++iq) {
        float4 v = *(const float4*)(act + iq * 4);
        #pragma unroll
        for (int di = 0; di < 4; ++di) {
            const float vv = (di == 0) ? v.x : (di == 1) ? v.y : (di == 2) ? v.z : v.w;
            const float* wr = Wj + (iq * 4 + di) * NOUT;
            if constexpr (JCN == 8) {
                float4 w0 = *(const float4*)(wr);
                float4 w1 = *(const float4*)(wr + 4);
                acc[0] = fmaf(vv, w0.x, acc[0]); acc[1] = fmaf(vv, w0.y, acc[1]);
                acc[2] = fmaf(vv, w0.z, acc[2]); acc[3] = fmaf(vv, w0.w, acc[3]);
                acc[4] = fmaf(vv, w1.x, acc[4]); acc[5] = fmaf(vv, w1.y, acc[5]);
                acc[6] = fmaf(vv, w1.z, acc[6]); acc[7] = fmaf(vv, w1.w, acc[7]);
            } else if constexpr (JCN == 4) {
                float4 w0 = *(const float4*)(wr);
                acc[0] = fmaf(vv, w0.x, acc[0]); acc[1] = fmaf(vv, w0.y, acc[1]);
                acc[2] = fmaf(vv, w0.z, acc[2]); acc[3] = fmaf(vv, w0.w, acc[3]);
            } else {
                float2 w0 = *(const float2*)(wr);
                acc[0] = fmaf(vv, w0.x, acc[0]); acc[1] = fmaf(vv, w0.y, acc[1]);
            }
        }
    }
}

__global__ __launch_bounds__(BLK, 4) void node_wlds(
    const float* __restrict__ tg, const float* __restrict__ xg,
    const float* __restrict__ zg,
    const float* __restrict__ eW1, const float* __restrict__ eb1,
    const float* __restrict__ eW2, const float* __restrict__ eb2,
    const float* __restrict__ eW3, const float* __restrict__ eb3,
    const float* __restrict__ oW1, const float* __restrict__ ob1,
    const float* __restrict__ oW2, const float* __restrict__ ob2,
    const float* __restrict__ oW3, const float* __restrict__ ob3,
    const float* __restrict__ dWg, const float* __restrict__ dbg,
    float* __restrict__ outg)
{
    __shared__ __align__(16) float wl[WTOT];         // 35.5 KB weights
    __shared__ __align__(16) float H[SMP][HSTR];     // 17.4 KB
    __shared__ __align__(16) float ZB[SMP][ZSTR];    //  9.2 KB   (total 62.1 KB)

    const int tid  = threadIdx.x;
    const int lane = tid & 63;                                   // sample
    const int wid  = __builtin_amdgcn_readfirstlane((int)(tid >> 6));
    const int k     = blockIdx.x >> 6;                           // 64 blocks / k
    const int b     = (blockIdx.x & 63) * SMP + lane;
    const int j0 = wid * 8;   // 64-wide layers
    const int j3 = wid * 4;   // 32-wide layer
    const int od = wid * 2;   // 16-wide decode

    // ---- stage per-k ODE weights + decoder into LDS (coalesced float4) ----
    {
        float4* wl4 = (float4*)wl;
        wl4[tid]        = ((const float4*)(oW1 + k * 2048))[tid];
        wl4[512 + tid]  = ((const float4*)(oW2 + k * 4096))[tid];
        wl4[1024 + tid] = ((const float4*)(oW2 + k * 4096))[512 + tid];
        wl4[1536 + tid] = ((const float4*)(oW3 + k * 2048))[tid];
        if (tid < 16)  wl4[2048 + tid] = ((const float4*)(ob1 + k * 64))[tid];
        else if (tid < 32)  wl4[2048 + tid] = ((const float4*)(ob2 + k * 64))[tid - 16];
        else if (tid < 40)  wl4[2048 + tid] = ((const float4*)(ob3 + k * 32))[tid - 32];
        if (tid < 128) wl4[2088 + tid] = ((const float4*)dWg)[tid];
        if (tid < 4)   wl4[2216 + tid] = ((const float4*)dbg)[tid];
    }
    __syncthreads();

    float* Hrow = &H[lane][0];
    float* Zrow = &ZB[lane][0];
    const float* wl1 = wl + WO_W1 + j0;
    const float* wl2 = wl + WO_W2 + j0;
    const float* wl3 = wl + WO_W3 + j3;
    const float* bl1 = wl + WO_B1 + j0;
    const float* bl2 = wl + WO_B2 + j0;
    const float* bl3 = wl + WO_B3 + j3;
    const float* wld = wl + WO_DW + od;
    const float* bld = wl + WO_DB + od;

    // ---- encoder input: concat(x[b,0,:16], z[b,:8]) -> ZB cols 0..23 ----
    if (wid == 0) {
        const float4* xr = (const float4*)(xg + (size_t)b * (TT * OBSN));
        float4* dst = (float4*)Zrow;
        dst[0] = xr[0]; dst[1] = xr[1]; dst[2] = xr[2]; dst[3] = xr[3];
        const float4* zr = (const float4*)(zg + (size_t)b * NSTAT);
        dst[4] = zr[0]; dst[5] = zr[1];
    }
    __syncthreads();

    float acc[8];
    // encoder L1 (global weights; once)
    dense_any<OBSN + NSTAT, HID, 8>(Zrow, eW1 + j0, eb1 + j0, acc);
    {
        float4* o = (float4*)(Hrow + j0);
        o[0] = make_float4(fast_tanh(acc[0]), fast_tanh(acc[1]), fast_tanh(acc[2]), fast_tanh(acc[3]));
        o[1] = make_float4(fast_tanh(acc[4]), fast_tanh(acc[5]), fast_tanh(acc[6]), fast_tanh(acc[7]));
    }
    __syncthreads();
    // encoder L2 (in-place H)
    dense_any<HID, HID, 8>(Hrow, eW2 + j0, eb2 + j0, acc);
    __syncthreads();   // all H reads complete
    {
        float4* o = (float4*)(Hrow + j0);
        o[0] = make_float4(fast_tanh(acc[0]), fast_tanh(acc[1]), fast_tanh(acc[2]), fast_tanh(acc[3]));
        o[1] = make_float4(fast_tanh(acc[4]), fast_tanh(acc[5]), fast_tanh(acc[6]), fast_tanh(acc[7]));
    }
    __syncthreads();
    // encoder L3 -> z0
    float zc[4];
    dense_any<HID, LAT, 4>(Hrow, eW3 + j3, eb3 + j3, zc);
    *(float4*)(Zrow + j3) = make_float4(zc[0], zc[1], zc[2], zc[3]);
    __syncthreads();

    float* outp = outg + ((size_t)(k * BB + b)) * (TT * OBSN) + od;

    // ---- decode t = 0 ----
    {
        float oa[2];
        dense_any<LAT, OBSN, 2>(Zrow, wld, bld, oa);
        *(float2*)outp = make_float2(oa[0], oa[1]);
    }

    // ---- RK4 time loop ----
    float tprev = tg[0];
    #pragma unroll 1
    for (int step = 1; step < TT; ++step) {
        const float tcur = tg[step];
        const float h = tcur - tprev;
        tprev = tcur;

        float zn[4];
        #pragma unroll
        for (int p = 0; p < 4; ++p) zn[p] = zc[p];

        #pragma unroll 1
        for (int stage = 0; stage < 4; ++stage) {
            // L1: ZB(32) -> H(64) tanh
            dense_any<LAT, HID, 8>(Zrow, wl1, bl1, acc);
            {
                float4* o = (float4*)(Hrow + j0);
                o[0] = make_float4(fast_tanh(acc[0]), fast_tanh(acc[1]), fast_tanh(acc[2]), fast_tanh(acc[3]));
                o[1] = make_float4(fast_tanh(acc[4]), fast_tanh(acc[5]), fast_tanh(acc[6]), fast_tanh(acc[7]));
            }
            __syncthreads();                       // B_A: h1 visible; all ZB reads done
            // L2: H(64) -> H(64) tanh, in place
            dense_any<HID, HID, 8>(Hrow, wl2, bl2, acc);
            __syncthreads();                       // B_B: all h1 reads complete
            {
                float4* o = (float4*)(Hrow + j0);
                o[0] = make_float4(fast_tanh(acc[0]), fast_tanh(acc[1]), fast_tanh(acc[2]), fast_tanh(acc[3]));
                o[1] = make_float4(fast_tanh(acc[4]), fast_tanh(acc[5]), fast_tanh(acc[6]), fast_tanh(acc[7]));
            }
            __syncthreads();                       // B_C: h2 visible
            // L3: H(64) -> f(32) chunk + RK4 combine
            float fo[4];
            dense_any<HID, LAT, 4>(Hrow, wl3, bl3, fo);

            const float czn = (stage == 0 || stage == 3) ? h * (1.0f / 6.0f)
                                                         : h * (1.0f / 3.0f);
            #pragma unroll
            for (int p = 0; p < 4; ++p) zn[p] = fmaf(czn, fo[p], zn[p]);

            if (stage < 3) {
                const float czt = (stage == 2) ? h : 0.5f * h;
                float4 zt;
                zt.x = fmaf(czt, fo[0], zc[0]);
                zt.y = fmaf(czt, fo[1], zc[1]);
                zt.z = fmaf(czt, fo[2], zc[2]);
                zt.w = fmaf(czt, fo[3], zc[3]);
                *(float4*)(Zrow + j3) = zt;
            } else {
                #pragma unroll
                for (int p = 0; p < 4; ++p) zc[p] = zn[p];
                *(float4*)(Zrow + j3) = make_float4(zn[0], zn[1], zn[2], zn[3]);
            }
            __syncthreads();                       // B_D: z_next visible; h2 reads done
        }

        // decode this step
        {
            float oa[2];
            dense_any<LAT, OBSN, 2>(Zrow, wld, bld, oa);
            *(float2*)(outp + (size_t)step * OBSN) = make_float2(oa[0], oa[1]);
        }
    }
}

extern "C" void kernel_launch(void* const* d_in, const int* in_sizes, int n_in,
                              void* d_out, int out_size, void* d_ws, size_t ws_size,
                              hipStream_t stream) {
    const float* tg  = (const float*)d_in[0];
    const float* xg  = (const float*)d_in[1];
    const float* zg  = (const float*)d_in[2];
    const float* eW1 = (const float*)d_in[3];
    const float* eb1 = (const float*)d_in[4];
    const float* eW2 = (const float*)d_in[5];
    const float* eb2 = (const float*)d_in[6];
    const float* eW3 = (const float*)d_in[7];
    const float* eb3 = (const float*)d_in[8];
    const float* oW1 = (const float*)d_in[9];
    const float* ob1 = (const float*)d_in[10];
    const float* oW2 = (const float*)d_in[11];
    const float* ob2 = (const float*)d_in[12];
    const float* oW3 = (const float*)d_in[13];
    const float* ob3 = (const float*)d_in[14];
    const float* dW  = (const float*)d_in[15];
    const float* db  = (const float*)d_in[16];
    float* outg = (float*)d_out;

    dim3 grid(NK * (BB / SMP));  // 8 * 64 = 512 blocks, 4096 waves
    node_wlds<<<grid, BLK, 0, stream>>>(
        tg, xg, zg, eW1, eb1, eW2, eb2, eW3, eb3,
        oW1, ob1, oW2, ob2, oW3, ob3, dW, db, outg);
}